// Round 12
// baseline (1713.292 us; speedup 1.0000x reference)
//
#include <hip/hip_runtime.h>
#include <math.h>

// Problem constants (fixed instance)
#define B_      512
#define T_      128
#define CIN_    64
#define H_      256
#define COUT_   64
#define OUT_T_  32
#define NB_     16            // batch rows per scan workgroup
#define NSTEP_  (T_ - 1)      // 127
#define HWIN_   (T_ - OUT_T_) // 96: first kept time index

#define WL_SCALE 1024.0f      // keep Wl out of f16-denormal range (MFMA flush risk)
#define WL_INV   0.0009765625f

typedef _Float16 half8  __attribute__((ext_vector_type(8)));
typedef float    floatx4 __attribute__((ext_vector_type(4)));

__device__ __forceinline__ float tanh_fast(float x){
  float e = __expf(2.0f * x);
  return 1.0f - 2.0f * __builtin_amdgcn_rcpf(e + 1.0f);
}
__device__ __forceinline__ float sigm_fast(float x){
  return __builtin_amdgcn_rcpf(1.0f + __expf(-x));
}

// Pack W[K][N] (f32 row-major) into fragment-linear f16 hi + scaled lo residual:
// P[((k>>5)*N + n)*32 + (k&31)]; a wave's B-fragment load (lane l reads 8
// contiguous f16 at k-offset 8*(l>>4), col n0+(l&15)) is one 16B load.
__global__ void pack_kernel(const float* __restrict__ W, _Float16* __restrict__ Ph,
                            _Float16* __restrict__ Pl, int K, int N){
  int i = blockIdx.x * blockDim.x + threadIdx.x;
  if (i >= K * N) return;
  int k = i / N, n = i - k * N;
  float w = W[i];
  _Float16 h = (_Float16)w;
  int idx = ((k >> 5) * N + n) * 32 + (k & 31);
  Ph[idx] = h;
  Pl[idx] = (_Float16)((w - (float)h) * WL_SCALE);
}

// --------------- scan kernel: 32 WGs x 1024 threads (16 waves) ---------------
// DEMAND-SHRINK strategy: the allocator always targets 4 waves/SIMD (128 VGPR)
// and remats anything above it (R5/R8/R9/R10 all VGPR=128 with streams; R11's
// hard-AGPR pin crashed). So fit UNDER 128: 16 waves, each owns 32 cols of ONE
// matrix (waves 0-7 Wf, 8-15 Wg) = 64 VGPR weights + 8 acc + ~45 state = ~117.
// No pressure => no remat => true residency at the allocator's preferred
// occupancy. Only Wl (256 KB/WG/step, L2-resident) is streamed.
// R9-verified numerics (absmax 2.0): per step
//   u += dzh@Wh + dzl@Wh + (dz*2^-10)@(Wl*2^10)   [scales cancel exactly]
// Phases: A: F computes f*dt, G computes g*sqdt*eps -> gpart | barA |
//         B: F forms dz, writes zs/zl/zss + zhist; G prefetches eps | barB |
//         C: all 16 waves MFMA (2 tiles x 8 kt x 3 channels = 48 MFMAs).
__global__ __launch_bounds__(1024, 4) void scan_kernel(
    const float* __restrict__ times,
    const float* __restrict__ coeffs,
    const float* __restrict__ noise,
    const float* __restrict__ W_init,
    const float* __restrict__ b_init,
    const float* __restrict__ bf,
    const float* __restrict__ bg,
    const _Float16* __restrict__ WfPh,
    const _Float16* __restrict__ WfPl,
    const _Float16* __restrict__ WgPh,
    const _Float16* __restrict__ WgPl,
    _Float16* __restrict__ zhist)
{
  __shared__ __align__(16) _Float16 zs [NB_ * H_];  // 8 KB swizzled (dzh / z0h)
  __shared__ __align__(16) _Float16 zl [NB_ * H_];  // 8 KB swizzled (dzl / z0l)
  __shared__ __align__(16) _Float16 zss[NB_ * H_];  // 8 KB swizzled (dz*2^-10)
  __shared__ float gpart[NB_][H_ + 1];              // 16.4 KB (+1 pad)
  __shared__ float x0_lds[NB_ * CIN_];              // 4 KB
  __shared__ float z0f[NB_ * H_];                   // 16 KB
  __shared__ float diffs[128];
  __shared__ float dtsh[2];

  const int tid  = threadIdx.x;
  const int lane = tid & 63;
  const int wv   = tid >> 6;    // wave 0..15
  const int lo   = lane & 15;
  const int hi   = lane >> 4;   // 0..3
  const int b0   = blockIdx.x * NB_;
  const bool isF = (wv < 8);
  const int  cw  = (wv & 7) * 32;   // this wave's 32-col slice

  const _Float16* __restrict__ Wh = isF ? WfPh : WgPh;
  const _Float16* __restrict__ Wl = isF ? WfPl : WgPl;
  const float*    __restrict__ bb = isF ? bf   : bg;

  if (tid < 127) diffs[tid] = times[tid + 1] - times[tid];
  if (tid == 127) diffs[127] = 3.4e38f;

  // Resident hi-weight fragments: 32 cols of ONE matrix = 64 VGPRs.
  half8 wh[2][8];
  #pragma unroll
  for (int t2 = 0; t2 < 2; ++t2){
    int n0 = cw + 16*t2 + lo;
    #pragma unroll
    for (int kt = 0; kt < 8; ++kt)
      wh[t2][kt] = *(const half8*)(Wh + (kt*H_ + n0)*32 + 8*hi);
  }
  float bv[2];
  #pragma unroll
  for (int t2 = 0; t2 < 2; ++t2) bv[t2] = bb[cw + 16*t2 + lo];

  for (int i = tid; i < NB_ * CIN_; i += 1024)
    x0_lds[i] = coeffs[(size_t)(b0 + (i >> 6)) * (T_ * CIN_) + (i & 63)];
  __syncthreads();

  if (tid < 64){
    float m = fminf(diffs[tid], diffs[tid + 64]);
    #pragma unroll
    for (int o = 32; o; o >>= 1) m = fminf(m, __shfl_down(m, o, 64));
    if (tid == 0){
      float dt0 = fmaxf(m, 0.001f);
      dtsh[0] = dt0; dtsh[1] = sqrtf(dt0);
    }
  }

  // z0 = x0 @ W_init + b_init (exact f32, VALU). 1024 threads: 4 cols each.
  {
    int r = tid & 15, c0 = (tid >> 4) * 4;   // tid>>4 in 0..63
    float acc[4];
    #pragma unroll
    for (int j = 0; j < 4; ++j) acc[j] = b_init[c0 + j];
    for (int k = 0; k < CIN_; ++k){
      float x = x0_lds[r * CIN_ + k];
      const float* wrow = W_init + k * H_ + c0;
      #pragma unroll
      for (int j = 0; j < 4; ++j) acc[j] += x * wrow[j];
    }
    #pragma unroll
    for (int j = 0; j < 4; ++j) z0f[r * H_ + c0 + j] = acc[j];
  }
  __syncthreads();

  const float dt = dtsh[0], sqdt = dtsh[1];

  // f32 master z: F-waves only (each owns 32 cols; 8 F-waves cover all 256)
  float zreg[2][4];
  if (isF){
    #pragma unroll
    for (int t2 = 0; t2 < 2; ++t2){
      int col = cw + 16*t2 + lo;
      #pragma unroll
      for (int rg = 0; rg < 4; ++rg)
        zreg[t2][rg] = z0f[(hi*4 + rg) * H_ + col];
    }
  }
  // Seed swizzled z0 tiles (hi, lo, scaled)
  for (int i = tid; i < NB_ * H_; i += 1024){
    int rr = i >> 8;
    float zv = z0f[i];
    _Float16 zh = (_Float16)zv;
    int idx = i ^ ((rr & 7) << 3);
    zs [idx] = zh;
    zl [idx] = (_Float16)(zv - (float)zh);
    zss[idx] = (_Float16)(zv * WL_INV);
  }
  __syncthreads();

  const int eb0 = (b0 + hi*4) * H_ + cw + lo;
  const size_t zh0 = (size_t)(b0 + hi*4) * (OUT_T_ * H_) + cw + lo;

  int aoff[8];
  #pragma unroll
  for (int kt = 0; kt < 8; ++kt)
    aoff[kt] = (lo*H_ + kt*32 + hi*8) ^ ((lo & 7) << 3);
  int woff[2][4];
  #pragma unroll
  for (int t2 = 0; t2 < 2; ++t2)
    #pragma unroll
    for (int rg = 0; rg < 4; ++rg){
      int row = hi*4 + rg;
      woff[t2][rg] = (row * H_ + cw + 16*t2 + lo) ^ ((row & 7) << 3);
    }

  // u0 = z0h@Wh + z0l@Wh + (z0*2^-10)@(Wl*2^10)
  floatx4 u[2];
  u[0] = (floatx4){0.f,0.f,0.f,0.f}; u[1] = u[0];
  #pragma unroll
  for (int kt = 0; kt < 8; ++kt){
    half8 ah = *(const half8*)&zs [aoff[kt]];
    half8 al = *(const half8*)&zl [aoff[kt]];
    half8 as_= *(const half8*)&zss[aoff[kt]];
    #pragma unroll
    for (int t2 = 0; t2 < 2; ++t2){
      half8 plw = *(const half8*)(Wl + (kt*H_ + cw + 16*t2 + lo)*32 + 8*hi);
      u[t2] = __builtin_amdgcn_mfma_f32_16x16x32_f16(ah,  wh[t2][kt], u[t2], 0,0,0);
      u[t2] = __builtin_amdgcn_mfma_f32_16x16x32_f16(al,  wh[t2][kt], u[t2], 0,0,0);
      u[t2] = __builtin_amdgcn_mfma_f32_16x16x32_f16(as_, plw,        u[t2], 0,0,0);
    }
  }

  // Prologue eps (s=0): G-waves only
  float eps[2][4];
  if (!isF){
    #pragma unroll
    for (int t2 = 0; t2 < 2; ++t2)
      #pragma unroll
      for (int rg = 0; rg < 4; ++rg)
        eps[t2][rg] = noise[eb0 + rg*H_ + t2*16];
  }

  unsigned int wlo = 0;   // opaque 0: blocks LICM/hoist of per-step Wl streams

  // ---------------- main sequential scan: two barriers per step ------------
  for (int s = 0; s < NSTEP_; ++s){
    // Phase A
    float fdt[2][4];
    if (isF){
      #pragma unroll
      for (int t2 = 0; t2 < 2; ++t2)
        #pragma unroll
        for (int rg = 0; rg < 4; ++rg)
          fdt[t2][rg] = tanh_fast(u[t2][rg] + bv[t2]) * dt;
    } else {
      #pragma unroll
      for (int t2 = 0; t2 < 2; ++t2)
        #pragma unroll
        for (int rg = 0; rg < 4; ++rg){
          float g = sigm_fast(u[t2][rg] + bv[t2]);
          gpart[hi*4 + rg][cw + 16*t2 + lo] = g * (sqdt * eps[t2][rg]);
        }
    }
    __syncthreads();   // barA: gpart visible; prior step's tile reads done

    // Phase B
    if (isF){
      #pragma unroll
      for (int t2 = 0; t2 < 2; ++t2)
        #pragma unroll
        for (int rg = 0; rg < 4; ++rg){
          int row = hi*4 + rg;
          float dz = fdt[t2][rg] + gpart[row][cw + 16*t2 + lo];
          _Float16 dh = (_Float16)dz;
          _Float16 dl2= (_Float16)(dz - (float)dh);
          _Float16 dss= (_Float16)(dz * WL_INV);
          zreg[t2][rg] += (float)dh + (float)dl2;   // master == what u tracks
          int wo = woff[t2][rg];
          zs [wo] = dh;
          zl [wo] = dl2;
          zss[wo] = dss;
        }
      if (s >= HWIN_ - 1){
        int sl = s - (HWIN_ - 1);
        #pragma unroll
        for (int t2 = 0; t2 < 2; ++t2)
          #pragma unroll
          for (int rg = 0; rg < 4; ++rg)
            zhist[zh0 + (size_t)rg*(OUT_T_*H_) + sl*H_ + t2*16] = (_Float16)zreg[t2][rg];
      }
    } else if (s + 1 < NSTEP_){
      const float* np_ = noise + (size_t)(s + 1) * (B_ * H_);
      #pragma unroll
      for (int t2 = 0; t2 < 2; ++t2)
        #pragma unroll
        for (int rg = 0; rg < 4; ++rg)
          eps[t2][rg] = np_[eb0 + rg*H_ + t2*16];
    }
    __syncthreads();   // barB: dz tiles visible

    // Phase C
    if (s + 1 < NSTEP_){
      const _Float16* wlp = (const _Float16*)((const char*)Wl + wlo);
      #pragma unroll
      for (int kt = 0; kt < 8; ++kt){
        half8 ah = *(const half8*)&zs [aoff[kt]];
        half8 al = *(const half8*)&zl [aoff[kt]];
        half8 as_= *(const half8*)&zss[aoff[kt]];
        #pragma unroll
        for (int t2 = 0; t2 < 2; ++t2){
          half8 plw = *(const half8*)(wlp + (kt*H_ + cw + 16*t2 + lo)*32 + 8*hi);
          u[t2] = __builtin_amdgcn_mfma_f32_16x16x32_f16(ah,  wh[t2][kt], u[t2], 0,0,0);
          u[t2] = __builtin_amdgcn_mfma_f32_16x16x32_f16(al,  wh[t2][kt], u[t2], 0,0,0);
          u[t2] = __builtin_amdgcn_mfma_f32_16x16x32_f16(as_, plw,        u[t2], 0,0,0);
        }
      }
    }
    asm volatile("" : "+v"(wlo));
  }
}

// ---------------- head kernel: pred_y = relu(h@W1+b1)@W2 + b2 ----------------
__global__ __launch_bounds__(256) void head_kernel(
    const _Float16* __restrict__ zhist,
    const _Float16* __restrict__ W1P,
    const _Float16* __restrict__ W2P,
    const float* __restrict__ b1,
    const float* __restrict__ b2,
    float* __restrict__ out)
{
  __shared__ __align__(16) _Float16 hbuf[64 * H_];  // 32 KB, swizzled
  __shared__ __align__(16) _Float16 ubuf[64 * H_];  // 32 KB, swizzled

  const int tid  = threadIdx.x;
  const int lane = tid & 63;
  const int wv   = tid >> 6;   // 0..3
  const int lo   = lane & 15;
  const int hi   = lane >> 4;
  const int m0   = blockIdx.x * 64;

  for (int c = tid; c < 64 * 32; c += 256){
    int rr = c >> 5, c8 = (c & 31) * 8;
    *(half8*)&hbuf[(rr * H_ + c8) ^ ((rr & 7) << 3)] =
        *(const half8*)&zhist[(size_t)(m0 + rr) * H_ + c8];
  }

  half8 w1f[4][8];
  #pragma unroll
  for (int nt = 0; nt < 4; ++nt){
    int n0 = 64*wv + 16*nt + lo;
    #pragma unroll
    for (int kt = 0; kt < 8; ++kt)
      w1f[nt][kt] = *(const half8*)(W1P + (kt*H_ + n0)*32 + 8*hi);
  }
  half8 w2f[8];
  #pragma unroll
  for (int kt = 0; kt < 8; ++kt)
    w2f[kt] = *(const half8*)(W2P + (kt*COUT_ + 16*wv + lo)*32 + 8*hi);

  float b1v[4];
  #pragma unroll
  for (int nt = 0; nt < 4; ++nt) b1v[nt] = b1[64*wv + 16*nt + lo];
  float b2v = b2[16*wv + lo];

  __syncthreads();

  // Stage 1: U = relu(h @ W1 + b1)
  for (int mt = 0; mt < 4; ++mt){
    half8 a[8];
    #pragma unroll
    for (int kt = 0; kt < 8; ++kt)
      a[kt] = *(const half8*)&hbuf[((mt*16 + lo) * H_ + kt*32 + hi*8) ^ ((lo & 7) << 3)];
    #pragma unroll
    for (int nt = 0; nt < 4; ++nt){
      floatx4 acc = {0.f,0.f,0.f,0.f};
      #pragma unroll
      for (int kt = 0; kt < 8; ++kt)
        acc = __builtin_amdgcn_mfma_f32_16x16x32_f16(a[kt], w1f[nt][kt], acc, 0,0,0);
      #pragma unroll
      for (int rg = 0; rg < 4; ++rg){
        float uu = fmaxf(acc[rg] + b1v[nt], 0.0f);
        int rr = mt*16 + hi*4 + rg;
        int cc = 64*wv + 16*nt + lo;
        ubuf[(rr * H_ + cc) ^ ((rr & 7) << 3)] = (_Float16)uu;
      }
    }
  }
  __syncthreads();

  // Stage 2: out = U @ W2 + b2
  for (int mt = 0; mt < 4; ++mt){
    half8 a[8];
    #pragma unroll
    for (int kt = 0; kt < 8; ++kt)
      a[kt] = *(const half8*)&ubuf[((mt*16 + lo) * H_ + kt*32 + hi*8) ^ ((lo & 7) << 3)];
    floatx4 acc = {0.f,0.f,0.f,0.f};
    #pragma unroll
    for (int kt = 0; kt < 8; ++kt)
      acc = __builtin_amdgcn_mfma_f32_16x16x32_f16(a[kt], w2f[kt], acc, 0,0,0);
    #pragma unroll
    for (int rg = 0; rg < 4; ++rg)
      out[(size_t)(m0 + mt*16 + hi*4 + rg) * COUT_ + 16*wv + lo] = acc[rg] + b2v;
  }
}

extern "C" void kernel_launch(void* const* d_in, const int* in_sizes, int n_in,
                              void* d_out, int out_size, void* d_ws, size_t ws_size,
                              hipStream_t stream) {
  const float* times  = (const float*)d_in[0];
  const float* coeffs = (const float*)d_in[1];
  const float* noise  = (const float*)d_in[2];
  const float* W_init = (const float*)d_in[3];
  const float* b_init = (const float*)d_in[4];
  const float* Wf     = (const float*)d_in[5];
  const float* bf     = (const float*)d_in[6];
  const float* Wg     = (const float*)d_in[7];
  const float* bg     = (const float*)d_in[8];
  const float* W1     = (const float*)d_in[9];
  const float* b1     = (const float*)d_in[10];
  const float* W2     = (const float*)d_in[11];
  const float* b2     = (const float*)d_in[12];

  // Workspace: zhist (8.39 MB) | 8 x 128KB packed-weight slots
  char* ws = (char*)d_ws;
  _Float16* zhist = (_Float16*)(ws);
  char* wbase = ws + 8388608;
  _Float16* WfPh = (_Float16*)(wbase + 0*131072);
  _Float16* WfPl = (_Float16*)(wbase + 1*131072);
  _Float16* WgPh = (_Float16*)(wbase + 2*131072);
  _Float16* WgPl = (_Float16*)(wbase + 3*131072);
  _Float16* W1Ph = (_Float16*)(wbase + 4*131072);
  _Float16* W1Pl = (_Float16*)(wbase + 5*131072);
  _Float16* W2Ph = (_Float16*)(wbase + 6*131072);
  _Float16* W2Pl = (_Float16*)(wbase + 7*131072);

  pack_kernel<<<(H_*H_ + 255)/256, 256, 0, stream>>>(Wf, WfPh, WfPl, H_, H_);
  pack_kernel<<<(H_*H_ + 255)/256, 256, 0, stream>>>(Wg, WgPh, WgPl, H_, H_);
  pack_kernel<<<(H_*H_ + 255)/256, 256, 0, stream>>>(W1, W1Ph, W1Pl, H_, H_);
  pack_kernel<<<(H_*COUT_ + 255)/256, 256, 0, stream>>>(W2, W2Ph, W2Pl, H_, COUT_);

  scan_kernel<<<B_ / NB_, 1024, 0, stream>>>(times, coeffs, noise, W_init, b_init,
                                             bf, bg, WfPh, WfPl, WgPh, WgPl, zhist);

  head_kernel<<<(B_ * OUT_T_) / 64, 256, 0, stream>>>(zhist, W1Ph, W2Ph, b1, b2,
                                                      (float*)d_out);
}

// Round 13
// 721.533 us; speedup vs baseline: 2.3745x; 2.3745x over previous
//
#include <hip/hip_runtime.h>
#include <hip/hip_fp8.h>
#include <math.h>

// Problem constants (fixed instance)
#define B_      512
#define T_      128
#define CIN_    64
#define H_      256
#define COUT_   64
#define OUT_T_  32
#define NB_     16            // batch rows per scan workgroup
#define NSTEP_  (T_ - 1)      // 127
#define HWIN_   (T_ - OUT_T_) // 96: first kept time index

#define INV16_  1.52587890625e-5f   // 2^-16 (fp8 Wl channel scale)

typedef _Float16 half8  __attribute__((ext_vector_type(8)));
typedef float    floatx4 __attribute__((ext_vector_type(4)));

// Dynamic LDS layout (152072 B total):
//   [0,131072)        W8l (fp8): F at 0, G at 65536   (static, staged once)
//   [131072,139264)   zs tile (f16 dzh, swizzled)
//   [139264,147456)   zl tile (f16 dzl, swizzled)
//   [147456,151552)   z8 tile (fp8 dz, swizzled)
//   [151552,152064)   diffs (128 f32)
//   [152064,152072)   dtsh
//   prologue aliases (consumed before W8l staged): x0 @0 (4KB), z0f @4096 (16KB)
#define LDS_TOTAL_ 152072

// light barrier: drain LDS only, leave global loads/stores in flight
#define BARRIER_LGKM() asm volatile("s_waitcnt lgkmcnt(0)\n\ts_barrier" ::: "memory")

__device__ __forceinline__ float tanh_fast(float x){
  float e = __expf(2.0f * x);
  return 1.0f - 2.0f * __builtin_amdgcn_rcpf(e + 1.0f);
}
__device__ __forceinline__ float sigm_fast(float x){
  return __builtin_amdgcn_rcpf(1.0f + __expf(-x));
}
__device__ __forceinline__ int swz8(int row){   // byte-xor for the fp8 tile
  return ((row & 3) << 5) ^ ((row & 4) << 1);
}

// Pack W[K][N] (f32) -> fragment-linear f16 hi (Ph) + fp8 residual*2^16 (P8).
// idx = ((k>>5)*N + n)*32 + (k&31): lane l reads 8 contiguous elems at
// k-offset 8*(l>>4), col n0+(l&15) as one 16B (f16) / 8B (fp8) load.
__global__ void pack_kernel(const float* __restrict__ W, _Float16* __restrict__ Ph,
                            unsigned char* __restrict__ P8, int K, int N){
  int i = blockIdx.x * blockDim.x + threadIdx.x;
  if (i >= K * N) return;
  int k = i / N, n = i - k * N;
  float w = W[i];
  _Float16 h = (_Float16)w;
  int idx = ((k >> 5) * N + n) * 32 + (k & 31);
  Ph[idx] = h;
  float resid = (w - (float)h) * 65536.0f;   // |resid| ~ O(1): fp8-normal range
  P8[idx] = __hip_cvt_float_to_fp8(resid, __HIP_SATFINITE, __HIP_E4M3);
}

// ---------------- scan kernel: 32 WGs x 512 threads (8 waves) ----------------
// Streamed bytes HALVED: Wh f16 (256 KB/WG/step) streams from L2 (the
// allocator always remats it — proven R5-R12); the Wl correction lives in LDS
// as fp8 (128 KB static) consumed by fp8 MFMA. Channels per step:
//   uF/uG   += dzh@Wh + dzl@Wh            (f16 MFMA, Wh streamed)
//   u8F/u8G += fp8(dz) @ fp8((W-Wh)*2^16) (fp8 MFMA, LDS-resident B)
//   u = uF + 2^-16*u8F + b
// Raw lgkm-only barriers keep global traffic in flight across steps.
__global__ __launch_bounds__(512, 2) void scan_kernel(
    const float* __restrict__ times,
    const float* __restrict__ coeffs,
    const float* __restrict__ noise,
    const float* __restrict__ W_init,
    const float* __restrict__ b_init,
    const float* __restrict__ bf,
    const float* __restrict__ bg,
    const _Float16* __restrict__ WfPh,
    const _Float16* __restrict__ WgPh,
    const unsigned char* __restrict__ W8lF,
    const unsigned char* __restrict__ W8lG,
    _Float16* __restrict__ zhist)
{
  extern __shared__ __align__(16) char dynlds[];
  unsigned char* w8lds = (unsigned char*)dynlds;              // 128 KB
  _Float16* zst   = (_Float16*)(dynlds + 131072);             // 8 KB
  _Float16* zlt   = (_Float16*)(dynlds + 139264);             // 8 KB
  unsigned char* z8t = (unsigned char*)(dynlds + 147456);     // 4 KB
  float* diffs = (float*)(dynlds + 151552);
  float* dtsh  = (float*)(dynlds + 152064);
  float* x0_lds = (float*)(dynlds);            // prologue alias
  float* z0f    = (float*)(dynlds + 4096);     // prologue alias

  const int tid  = threadIdx.x;
  const int lane = tid & 63;
  const int wv   = tid >> 6;    // wave 0..7
  const int lo   = lane & 15;
  const int hi   = lane >> 4;   // 0..3
  const int b0   = blockIdx.x * NB_;

  if (tid < 127) diffs[tid] = times[tid + 1] - times[tid];
  if (tid == 127) diffs[127] = 3.4e38f;

  float bfv[2], bgv[2];
  #pragma unroll
  for (int t2 = 0; t2 < 2; ++t2){
    bfv[t2] = bf[32*wv + 16*t2 + lo];
    bgv[t2] = bg[32*wv + 16*t2 + lo];
  }

  for (int i = tid; i < NB_ * CIN_; i += 512)
    x0_lds[i] = coeffs[(size_t)(b0 + (i >> 6)) * (T_ * CIN_) + (i & 63)];
  __syncthreads();

  if (tid < 64){
    float m = fminf(diffs[tid], diffs[tid + 64]);
    #pragma unroll
    for (int o = 32; o; o >>= 1) m = fminf(m, __shfl_down(m, o, 64));
    if (tid == 0){
      float dt0 = fmaxf(m, 0.001f);
      dtsh[0] = dt0; dtsh[1] = sqrtf(dt0);
    }
  }

  // z0 = x0 @ W_init + b_init (exact f32, VALU)
  {
    int r = tid & 15, c0 = (tid >> 4) * 8;   // tid>>4 in 0..31
    float acc[8];
    #pragma unroll
    for (int j = 0; j < 8; ++j) acc[j] = b_init[c0 + j];
    for (int k = 0; k < CIN_; ++k){
      float x = x0_lds[r * CIN_ + k];
      const float* wrow = W_init + k * H_ + c0;
      #pragma unroll
      for (int j = 0; j < 8; ++j) acc[j] += x * wrow[j];
    }
    #pragma unroll
    for (int j = 0; j < 8; ++j) z0f[r * H_ + c0 + j] = acc[j];
  }
  __syncthreads();

  const float dt = dtsh[0], sqdt = dtsh[1];

  // f32 master z (C/D layout: col = lane&15 + 16*t2 + 32*wv, row = 4*hi+rg)
  float zreg[2][4];
  #pragma unroll
  for (int t2 = 0; t2 < 2; ++t2){
    int col = 32*wv + 16*t2 + lo;
    #pragma unroll
    for (int rg = 0; rg < 4; ++rg)
      zreg[t2][rg] = z0f[(hi*4 + rg) * H_ + col];
  }
  // Seed tiles from z0 (hi f16 / lo f16 / fp8)
  for (int i = tid; i < NB_ * H_; i += 512){
    int rr = i >> 8, cc = i & 255;
    float zv = z0f[i];
    _Float16 zh = (_Float16)zv;
    int idx = i ^ ((rr & 7) << 3);
    zst[idx] = zh;
    zlt[idx] = (_Float16)(zv - (float)zh);
    z8t[(rr * H_ + cc) ^ swz8(rr)] =
        __hip_cvt_float_to_fp8(zv, __HIP_SATFINITE, __HIP_E4M3);
  }
  __syncthreads();   // z0f consumed; safe to overwrite with W8l

  // Stage W8l (fp8, both matrices) into LDS: 128 KB, 16B per thread per iter
  for (int i = tid * 16; i < 65536; i += 512 * 16){
    *(int4*)(w8lds + i)         = *(const int4*)(W8lF + i);
    *(int4*)(w8lds + 65536 + i) = *(const int4*)(W8lG + i);
  }
  __syncthreads();

  const int n0a = 32*wv + lo;
  const int eb0 = (b0 + hi*4) * H_ + 32*wv + lo;
  const size_t zh0 = (size_t)(b0 + hi*4) * (OUT_T_ * H_) + 32*wv + lo;

  int aoff[8], a8off[8];
  #pragma unroll
  for (int kt = 0; kt < 8; ++kt){
    aoff[kt]  = (lo*H_ + kt*32 + hi*8) ^ ((lo & 7) << 3);
    a8off[kt] = (lo*H_ + kt*32 + hi*8) ^ swz8(lo);
  }
  int woff[2][4], w8off_[2][4];
  #pragma unroll
  for (int t2 = 0; t2 < 2; ++t2)
    #pragma unroll
    for (int rg = 0; rg < 4; ++rg){
      int row = hi*4 + rg, col = 32*wv + 16*t2 + lo;
      woff[t2][rg]   = (row * H_ + col) ^ ((row & 7) << 3);
      w8off_[t2][rg] = (row * H_ + col) ^ swz8(row);
    }

  // Accumulators: u0 = z0h@Wh + z0l@Wh + fp8(z0)@W8l
  floatx4 uF[2], uG[2], u8F[2], u8G[2];
  uF[0] = (floatx4){0.f,0.f,0.f,0.f}; uF[1] = uF[0];
  uG[0] = uF[0]; uG[1] = uF[0];
  u8F[0] = uF[0]; u8F[1] = uF[0]; u8G[0] = uF[0]; u8G[1] = uF[0];
  #pragma unroll
  for (int kt = 0; kt < 8; ++kt){
    half8 ah = *(const half8*)&zst[aoff[kt]];
    half8 al = *(const half8*)&zlt[aoff[kt]];
    long  a8 = *(const long*)&z8t[a8off[kt]];
    #pragma unroll
    for (int t2 = 0; t2 < 2; ++t2){
      int eidx = (kt*H_ + n0a + 16*t2)*32 + 8*hi;
      half8 whf = *(const half8*)(WfPh + eidx);
      half8 whg = *(const half8*)(WgPh + eidx);
      long  w8f = *(const long*)(w8lds + eidx);
      long  w8g = *(const long*)(w8lds + 65536 + eidx);
      uF[t2]  = __builtin_amdgcn_mfma_f32_16x16x32_f16(ah, whf, uF[t2], 0,0,0);
      uF[t2]  = __builtin_amdgcn_mfma_f32_16x16x32_f16(al, whf, uF[t2], 0,0,0);
      uG[t2]  = __builtin_amdgcn_mfma_f32_16x16x32_f16(ah, whg, uG[t2], 0,0,0);
      uG[t2]  = __builtin_amdgcn_mfma_f32_16x16x32_f16(al, whg, uG[t2], 0,0,0);
      u8F[t2] = __builtin_amdgcn_mfma_f32_16x16x32_fp8_fp8(a8, w8f, u8F[t2], 0,0,0);
      u8G[t2] = __builtin_amdgcn_mfma_f32_16x16x32_fp8_fp8(a8, w8g, u8G[t2], 0,0,0);
    }
  }

  // Prologue eps (s=0)
  float eps[2][4];
  #pragma unroll
  for (int t2 = 0; t2 < 2; ++t2)
    #pragma unroll
    for (int rg = 0; rg < 4; ++rg)
      eps[t2][rg] = noise[eb0 + rg*H_ + t2*16];

  __syncthreads();   // protect tiles until all waves consumed seed reads

  unsigned int wlo = 0;   // opaque 0: keeps Wh streams loop-variant (no hoist)

  // -------- main scan: 2 light barriers/step, single-buffered tiles --------
  for (int s = 0; s < NSTEP_; ++s){
    // VALU phase (u complete from prev step's MFMA phase)
    _Float16 dzh[2][4], dzl[2][4];
    unsigned char dz8[2][4];
    #pragma unroll
    for (int t2 = 0; t2 < 2; ++t2)
      #pragma unroll
      for (int rg = 0; rg < 4; ++rg){
        float uf = fmaf(INV16_, u8F[t2][rg], uF[t2][rg]) + bfv[t2];
        float ug = fmaf(INV16_, u8G[t2][rg], uG[t2][rg]) + bgv[t2];
        float f = tanh_fast(uf);
        float g = sigm_fast(ug);
        float dz = fmaf(g, sqdt * eps[t2][rg], f * dt);
        _Float16 dh = (_Float16)dz;
        _Float16 dl = (_Float16)(dz - (float)dh);
        dzh[t2][rg] = dh; dzl[t2][rg] = dl;
        dz8[t2][rg] = __hip_cvt_float_to_fp8(dz, __HIP_SATFINITE, __HIP_E4M3);
        zreg[t2][rg] += (float)dh + (float)dl;   // master == what u tracks
      }

    // Tile writes (single buffer: prev step's reads completed at last barB)
    #pragma unroll
    for (int t2 = 0; t2 < 2; ++t2)
      #pragma unroll
      for (int rg = 0; rg < 4; ++rg){
        zst[woff[t2][rg]] = dzh[t2][rg];
        zlt[woff[t2][rg]] = dzl[t2][rg];
        z8t[w8off_[t2][rg]] = dz8[t2][rg];
      }

    BARRIER_LGKM();   // barA: tiles visible; global traffic stays in flight

    if (s + 1 < NSTEP_){
      const float* np_ = noise + (size_t)(s + 1) * (B_ * H_);
      #pragma unroll
      for (int t2 = 0; t2 < 2; ++t2)
        #pragma unroll
        for (int rg = 0; rg < 4; ++rg)
          eps[t2][rg] = np_[eb0 + rg*H_ + t2*16];
    }
    if (s >= HWIN_ - 1){
      int sl = s - (HWIN_ - 1);
      #pragma unroll
      for (int t2 = 0; t2 < 2; ++t2)
        #pragma unroll
        for (int rg = 0; rg < 4; ++rg)
          zhist[zh0 + (size_t)rg*(OUT_T_*H_) + sl*H_ + t2*16] = (_Float16)zreg[t2][rg];
    }

    if (s + 1 < NSTEP_){
      const _Float16* wfp = (const _Float16*)((const char*)WfPh + wlo);
      const _Float16* wgp = (const _Float16*)((const char*)WgPh + wlo);
      #pragma unroll
      for (int kt = 0; kt < 8; ++kt){
        half8 ah = *(const half8*)&zst[aoff[kt]];
        half8 al = *(const half8*)&zlt[aoff[kt]];
        long  a8 = *(const long*)&z8t[a8off[kt]];
        #pragma unroll
        for (int t2 = 0; t2 < 2; ++t2){
          int eidx = (kt*H_ + n0a + 16*t2)*32 + 8*hi;
          half8 whf = *(const half8*)(wfp + eidx);      // streamed from L2
          half8 whg = *(const half8*)(wgp + eidx);
          long  w8f = *(const long*)(w8lds + eidx);     // LDS-resident
          long  w8g = *(const long*)(w8lds + 65536 + eidx);
          uF[t2]  = __builtin_amdgcn_mfma_f32_16x16x32_f16(ah, whf, uF[t2], 0,0,0);
          uF[t2]  = __builtin_amdgcn_mfma_f32_16x16x32_f16(al, whf, uF[t2], 0,0,0);
          uG[t2]  = __builtin_amdgcn_mfma_f32_16x16x32_f16(ah, whg, uG[t2], 0,0,0);
          uG[t2]  = __builtin_amdgcn_mfma_f32_16x16x32_f16(al, whg, uG[t2], 0,0,0);
          u8F[t2] = __builtin_amdgcn_mfma_f32_16x16x32_fp8_fp8(a8, w8f, u8F[t2], 0,0,0);
          u8G[t2] = __builtin_amdgcn_mfma_f32_16x16x32_fp8_fp8(a8, w8g, u8G[t2], 0,0,0);
        }
      }
    }

    BARRIER_LGKM();   // barB: this step's tile reads done before next write
    asm volatile("" : "+v"(wlo));
  }
}

// ---------------- head kernel: pred_y = relu(h@W1+b1)@W2 + b2 ----------------
__global__ __launch_bounds__(256) void head_kernel(
    const _Float16* __restrict__ zhist,
    const _Float16* __restrict__ W1P,
    const _Float16* __restrict__ W2P,
    const float* __restrict__ b1,
    const float* __restrict__ b2,
    float* __restrict__ out)
{
  __shared__ __align__(16) _Float16 hbuf[64 * H_];  // 32 KB, swizzled
  __shared__ __align__(16) _Float16 ubuf[64 * H_];  // 32 KB, swizzled

  const int tid  = threadIdx.x;
  const int lane = tid & 63;
  const int wv   = tid >> 6;   // 0..3
  const int lo   = lane & 15;
  const int hi   = lane >> 4;
  const int m0   = blockIdx.x * 64;

  for (int c = tid; c < 64 * 32; c += 256){
    int rr = c >> 5, c8 = (c & 31) * 8;
    *(half8*)&hbuf[(rr * H_ + c8) ^ ((rr & 7) << 3)] =
        *(const half8*)&zhist[(size_t)(m0 + rr) * H_ + c8];
  }

  half8 w1f[4][8];
  #pragma unroll
  for (int nt = 0; nt < 4; ++nt){
    int n0 = 64*wv + 16*nt + lo;
    #pragma unroll
    for (int kt = 0; kt < 8; ++kt)
      w1f[nt][kt] = *(const half8*)(W1P + (kt*H_ + n0)*32 + 8*hi);
  }
  half8 w2f[8];
  #pragma unroll
  for (int kt = 0; kt < 8; ++kt)
    w2f[kt] = *(const half8*)(W2P + (kt*COUT_ + 16*wv + lo)*32 + 8*hi);

  float b1v[4];
  #pragma unroll
  for (int nt = 0; nt < 4; ++nt) b1v[nt] = b1[64*wv + 16*nt + lo];
  float b2v = b2[16*wv + lo];

  __syncthreads();

  // Stage 1: U = relu(h @ W1 + b1)
  for (int mt = 0; mt < 4; ++mt){
    half8 a[8];
    #pragma unroll
    for (int kt = 0; kt < 8; ++kt)
      a[kt] = *(const half8*)&hbuf[((mt*16 + lo) * H_ + kt*32 + hi*8) ^ ((lo & 7) << 3)];
    #pragma unroll
    for (int nt = 0; nt < 4; ++nt){
      floatx4 acc = {0.f,0.f,0.f,0.f};
      #pragma unroll
      for (int kt = 0; kt < 8; ++kt)
        acc = __builtin_amdgcn_mfma_f32_16x16x32_f16(a[kt], w1f[nt][kt], acc, 0,0,0);
      #pragma unroll
      for (int rg = 0; rg < 4; ++rg){
        float u = fmaxf(acc[rg] + b1v[nt], 0.0f);
        int rr = mt*16 + hi*4 + rg;
        int cc = 64*wv + 16*nt + lo;
        ubuf[(rr * H_ + cc) ^ ((rr & 7) << 3)] = (_Float16)u;
      }
    }
  }
  __syncthreads();

  // Stage 2: out = U @ W2 + b2
  for (int mt = 0; mt < 4; ++mt){
    half8 a[8];
    #pragma unroll
    for (int kt = 0; kt < 8; ++kt)
      a[kt] = *(const half8*)&ubuf[((mt*16 + lo) * H_ + kt*32 + hi*8) ^ ((lo & 7) << 3)];
    floatx4 acc = {0.f,0.f,0.f,0.f};
    #pragma unroll
    for (int kt = 0; kt < 8; ++kt)
      acc = __builtin_amdgcn_mfma_f32_16x16x32_f16(a[kt], w2f[kt], acc, 0,0,0);
    #pragma unroll
    for (int rg = 0; rg < 4; ++rg)
      out[(size_t)(m0 + mt*16 + hi*4 + rg) * COUT_ + 16*wv + lo] = acc[rg] + b2v;
  }
}

extern "C" void kernel_launch(void* const* d_in, const int* in_sizes, int n_in,
                              void* d_out, int out_size, void* d_ws, size_t ws_size,
                              hipStream_t stream) {
  const float* times  = (const float*)d_in[0];
  const float* coeffs = (const float*)d_in[1];
  const float* noise  = (const float*)d_in[2];
  const float* W_init = (const float*)d_in[3];
  const float* b_init = (const float*)d_in[4];
  const float* Wf     = (const float*)d_in[5];
  const float* bf     = (const float*)d_in[6];
  const float* Wg     = (const float*)d_in[7];
  const float* bg     = (const float*)d_in[8];
  const float* W1     = (const float*)d_in[9];
  const float* b1     = (const float*)d_in[10];
  const float* W2     = (const float*)d_in[11];
  const float* b2     = (const float*)d_in[12];

  // Workspace layout
  char* ws = (char*)d_ws;
  _Float16*      zhist = (_Float16*)(ws);                    // 8388608
  _Float16*      WfPh  = (_Float16*)(ws + 8388608);          // 131072
  _Float16*      WgPh  = (_Float16*)(ws + 8519680);          // 131072
  unsigned char* W8lF  = (unsigned char*)(ws + 8650752);     // 65536
  unsigned char* W8lG  = (unsigned char*)(ws + 8716288);     // 65536
  _Float16*      W1Ph  = (_Float16*)(ws + 8781824);          // 131072
  unsigned char* W1P8  = (unsigned char*)(ws + 8912896);     // 65536 (unused)
  _Float16*      W2Ph  = (_Float16*)(ws + 8978432);          // 32768
  unsigned char* W2P8  = (unsigned char*)(ws + 9011200);     // 16384 (unused)

  pack_kernel<<<(H_*H_ + 255)/256, 256, 0, stream>>>(Wf, WfPh, W8lF, H_, H_);
  pack_kernel<<<(H_*H_ + 255)/256, 256, 0, stream>>>(Wg, WgPh, W8lG, H_, H_);
  pack_kernel<<<(H_*H_ + 255)/256, 256, 0, stream>>>(W1, W1Ph, W1P8, H_, H_);
  pack_kernel<<<(H_*COUT_ + 255)/256, 256, 0, stream>>>(W2, W2Ph, W2P8, H_, COUT_);

  hipFuncSetAttribute((const void*)scan_kernel,
                      hipFuncAttributeMaxDynamicSharedMemorySize, LDS_TOTAL_);
  scan_kernel<<<B_ / NB_, 512, LDS_TOTAL_, stream>>>(
      times, coeffs, noise, W_init, b_init, bf, bg,
      WfPh, WgPh, W8lF, W8lG, zhist);

  head_kernel<<<(B_ * OUT_T_) / 64, 256, 0, stream>>>(zhist, W1Ph, W2Ph, b1, b2,
                                                      (float*)d_out);
}

// Round 14
// 542.091 us; speedup vs baseline: 3.1605x; 1.3310x over previous
//
#include <hip/hip_runtime.h>
#include <hip/hip_fp8.h>
#include <math.h>

// Problem constants (fixed instance)
#define B_      512
#define T_      128
#define CIN_    64
#define H_      256
#define COUT_   64
#define OUT_T_  32
#define NB_     16            // batch rows per scan workgroup
#define NSTEP_  (T_ - 1)      // 127
#define HWIN_   (T_ - OUT_T_) // 96: first kept time index

#define INV16_  1.52587890625e-5f   // 2^-16 (fp8 Wl channel scale)

typedef _Float16 half8  __attribute__((ext_vector_type(8)));
typedef float    floatx4 __attribute__((ext_vector_type(4)));

// Dynamic LDS layout (152072 B total) — same as R13:
//   [0,131072)      W8l fp8 (F at 0, G at 65536), staged once
//   [131072,139264) zst (f16 dzh, swizzled)
//   [139264,147456) zlt (f16 dzl, swizzled)
//   [147456,151552) z8t (fp8 dz, f8-swizzled)
//   [151552,152064) diffs ; [152064,152072) dtsh
//   prologue aliases: x0 @0 (4KB), z0f @4096 (16KB)
#define LDS_TOTAL_ 152072

// light barrier: drain LDS only, leave global traffic in flight
#define BARRIER_LGKM() asm volatile("s_waitcnt lgkmcnt(0)\n\ts_barrier" ::: "memory")

__device__ __forceinline__ float tanh_fast(float x){
  float e = __expf(2.0f * x);
  return 1.0f - 2.0f * __builtin_amdgcn_rcpf(e + 1.0f);
}
__device__ __forceinline__ float sigm_fast(float x){
  return __builtin_amdgcn_rcpf(1.0f + __expf(-x));
}
// z8 tile swizzle: distinct bank-pair per row within a 16-lane group (4-way =
// b64 floor; R13's broken swz8 was 16-way = 14.3M conflict-cycles/dispatch)
__device__ __forceinline__ int f8swz(int r){
  return ((r & 3) << 5) | (((r >> 2) & 3) << 3);
}

// Pack Wf/Wg: f16 hi in WAVE-MAJOR fragment blocks (so the scan's per-thread
// load address is a step-invariant constant + imm offset), fp8 residual*2^16
// in the R13 fragment-linear layout (consumed from LDS).
// f16: elem (k,n) -> block (n>>5)*16 + (k>>5)*2 + ((n>>4)&1), 1KB blocks,
//      lane (hi*16+lo) holds 16B, j=k&7 consecutive.
__global__ void packFG_kernel(const float* __restrict__ W, _Float16* __restrict__ Ph,
                              unsigned char* __restrict__ P8){
  int i = blockIdx.x * blockDim.x + threadIdx.x;
  if (i >= H_ * H_) return;
  int k = i >> 8, n = i & 255;
  float w = W[i];
  _Float16 h = (_Float16)w;
  int off16 = (((n >> 5) * 16 + (k >> 5) * 2 + ((n >> 4) & 1)) << 10)
            + ((((k >> 3) & 3) * 16 + (n & 15)) << 4) + ((k & 7) << 1);
  *(_Float16*)((char*)Ph + off16) = h;
  P8[((k >> 5) * H_ + n) * 32 + (k & 31)] =
      __hip_cvt_float_to_fp8((w - (float)h) * 65536.0f, __HIP_SATFINITE, __HIP_E4M3);
}

// Old fragment-linear f16 pack for the head's W1/W2
__global__ void pack_kernel(const float* __restrict__ W, _Float16* __restrict__ Ph,
                            int K, int N){
  int i = blockIdx.x * blockDim.x + threadIdx.x;
  if (i >= K * N) return;
  int k = i / N, n = i - k * N;
  Ph[((k >> 5) * N + n) * 32 + (k & 31)] = (_Float16)W[i];
}

// ---------------- scan kernel: 32 WGs x 512 threads (8 waves) ----------------
// R13 numerics (absmax 2.75) unchanged:
//   uF/uG   += dzh@Wh + dzl@Wh            (f16 MFMA, Wh streamed from L2)
//   u8F/u8G += fp8(dz) @ fp8((W-Wh)*2^16) (fp8 MFMA, LDS-resident B)
//   u = uF + 2^-16*u8F + b
// NEW: wave-major Wh layout (imm-folded addressing, ~120 VALU/step saved),
// explicit 2-kt-deep Wh register prefetch, pointer-bumped eps loads,
// fixed z8 tile swizzle. Light lgkm-only barriers (R13-validated).
__global__ __launch_bounds__(512, 2) void scan_kernel(
    const float* __restrict__ times,
    const float* __restrict__ coeffs,
    const float* __restrict__ noise,
    const float* __restrict__ W_init,
    const float* __restrict__ b_init,
    const float* __restrict__ bf,
    const float* __restrict__ bg,
    const _Float16* __restrict__ WfPh,
    const _Float16* __restrict__ WgPh,
    const unsigned char* __restrict__ W8lF,
    const unsigned char* __restrict__ W8lG,
    _Float16* __restrict__ zhist)
{
  extern __shared__ __align__(16) char dynlds[];
  unsigned char* w8lds = (unsigned char*)dynlds;              // 128 KB
  _Float16* zst   = (_Float16*)(dynlds + 131072);             // 8 KB
  _Float16* zlt   = (_Float16*)(dynlds + 139264);             // 8 KB
  unsigned char* z8t = (unsigned char*)(dynlds + 147456);     // 4 KB
  float* diffs = (float*)(dynlds + 151552);
  float* dtsh  = (float*)(dynlds + 152064);
  float* x0_lds = (float*)(dynlds);            // prologue alias
  float* z0f    = (float*)(dynlds + 4096);     // prologue alias

  const int tid  = threadIdx.x;
  const int lane = tid & 63;
  const int wv   = tid >> 6;    // wave 0..7
  const int lo   = lane & 15;
  const int hi   = lane >> 4;   // 0..3
  const int b0   = blockIdx.x * NB_;

  if (tid < 127) diffs[tid] = times[tid + 1] - times[tid];
  if (tid == 127) diffs[127] = 3.4e38f;

  float bfv[2], bgv[2];
  #pragma unroll
  for (int t2 = 0; t2 < 2; ++t2){
    bfv[t2] = bf[32*wv + 16*t2 + lo];
    bgv[t2] = bg[32*wv + 16*t2 + lo];
  }

  for (int i = tid; i < NB_ * CIN_; i += 512)
    x0_lds[i] = coeffs[(size_t)(b0 + (i >> 6)) * (T_ * CIN_) + (i & 63)];
  __syncthreads();

  if (tid < 64){
    float m = fminf(diffs[tid], diffs[tid + 64]);
    #pragma unroll
    for (int o = 32; o; o >>= 1) m = fminf(m, __shfl_down(m, o, 64));
    if (tid == 0){
      float dt0 = fmaxf(m, 0.001f);
      dtsh[0] = dt0; dtsh[1] = sqrtf(dt0);
    }
  }

  // z0 = x0 @ W_init + b_init (exact f32, VALU)
  {
    int r = tid & 15, c0 = (tid >> 4) * 8;   // tid>>4 in 0..31
    float acc[8];
    #pragma unroll
    for (int j = 0; j < 8; ++j) acc[j] = b_init[c0 + j];
    for (int k = 0; k < CIN_; ++k){
      float x = x0_lds[r * CIN_ + k];
      const float* wrow = W_init + k * H_ + c0;
      #pragma unroll
      for (int j = 0; j < 8; ++j) acc[j] += x * wrow[j];
    }
    #pragma unroll
    for (int j = 0; j < 8; ++j) z0f[r * H_ + c0 + j] = acc[j];
  }
  __syncthreads();

  const float dt = dtsh[0], sqdt = dtsh[1];

  // f32 master z (C/D layout: col = lane&15 + 16*t2 + 32*wv, row = 4*hi+rg)
  float zreg[2][4];
  #pragma unroll
  for (int t2 = 0; t2 < 2; ++t2){
    int col = 32*wv + 16*t2 + lo;
    #pragma unroll
    for (int rg = 0; rg < 4; ++rg)
      zreg[t2][rg] = z0f[(hi*4 + rg) * H_ + col];
  }
  // Seed tiles from z0 (hi f16 / lo f16 / fp8)
  for (int i = tid; i < NB_ * H_; i += 512){
    int rr = i >> 8;
    float zv = z0f[i];
    _Float16 zh = (_Float16)zv;
    int idx = i ^ ((rr & 7) << 3);
    zst[idx] = zh;
    zlt[idx] = (_Float16)(zv - (float)zh);
    z8t[i ^ f8swz(rr)] = __hip_cvt_float_to_fp8(zv, __HIP_SATFINITE, __HIP_E4M3);
  }
  __syncthreads();   // z0f consumed; safe to overwrite with W8l

  // Stage W8l (fp8, both matrices) into LDS: 128 KB
  for (int i = tid * 16; i < 65536; i += 512 * 16){
    *(int4*)(w8lds + i)         = *(const int4*)(W8lF + i);
    *(int4*)(w8lds + 65536 + i) = *(const int4*)(W8lG + i);
  }
  __syncthreads();

  const int n0a = 32*wv + lo;
  const int eb0 = (b0 + hi*4) * H_ + 32*wv + lo;
  const size_t zh0 = (size_t)(b0 + hi*4) * (OUT_T_ * H_) + 32*wv + lo;

  // Wave-major Wh addressing: per-thread constant base (bytes)
  const int wb16 = (wv << 14) + (((hi << 4) + lo) << 4);
  const char* pfB = (const char*)WfPh + wb16;
  const char* pgB = (const char*)WgPh + wb16;

  int aoff[8], a8off[8];
  #pragma unroll
  for (int kt = 0; kt < 8; ++kt){
    aoff[kt]  = (lo*H_ + kt*32 + hi*8) ^ ((lo & 7) << 3);
    a8off[kt] = (lo*H_ + kt*32 + hi*8) ^ f8swz(lo);
  }
  int woff[2][4], w8off_[2][4];
  #pragma unroll
  for (int t2 = 0; t2 < 2; ++t2)
    #pragma unroll
    for (int rg = 0; rg < 4; ++rg){
      int row = hi*4 + rg, col = 32*wv + 16*t2 + lo;
      woff[t2][rg]   = (row * H_ + col) ^ ((row & 7) << 3);
      w8off_[t2][rg] = (row * H_ + col) ^ f8swz(row);
    }

  // u0 = z0h@Wh + z0l@Wh + fp8(z0)@W8l
  floatx4 uF[2], uG[2], u8F[2], u8G[2];
  uF[0] = (floatx4){0.f,0.f,0.f,0.f}; uF[1] = uF[0];
  uG[0] = uF[0]; uG[1] = uF[0];
  u8F[0] = uF[0]; u8F[1] = uF[0]; u8G[0] = uF[0]; u8G[1] = uF[0];
  #pragma unroll
  for (int kt = 0; kt < 8; ++kt){
    half8 ah = *(const half8*)&zst[aoff[kt]];
    half8 al = *(const half8*)&zlt[aoff[kt]];
    long  a8 = *(const long*)&z8t[a8off[kt]];
    #pragma unroll
    for (int t2 = 0; t2 < 2; ++t2){
      half8 whf = *(const half8*)(pfB + (kt*2 + t2)*1024);
      half8 whg = *(const half8*)(pgB + (kt*2 + t2)*1024);
      int eidx = (kt*H_ + n0a + 16*t2)*32 + 8*hi;
      long w8f = *(const long*)(w8lds + eidx);
      long w8g = *(const long*)(w8lds + 65536 + eidx);
      uF[t2]  = __builtin_amdgcn_mfma_f32_16x16x32_f16(ah, whf, uF[t2], 0,0,0);
      uF[t2]  = __builtin_amdgcn_mfma_f32_16x16x32_f16(al, whf, uF[t2], 0,0,0);
      uG[t2]  = __builtin_amdgcn_mfma_f32_16x16x32_f16(ah, whg, uG[t2], 0,0,0);
      uG[t2]  = __builtin_amdgcn_mfma_f32_16x16x32_f16(al, whg, uG[t2], 0,0,0);
      u8F[t2] = __builtin_amdgcn_mfma_f32_16x16x32_fp8_fp8(a8, w8f, u8F[t2], 0,0,0);
      u8G[t2] = __builtin_amdgcn_mfma_f32_16x16x32_fp8_fp8(a8, w8g, u8G[t2], 0,0,0);
    }
  }

  // eps pointer (per-thread, bumped per step) + prologue load (s=0)
  const char* epp = (const char*)(noise + eb0);
  float eps[2][4];
  #pragma unroll
  for (int t2 = 0; t2 < 2; ++t2)
    #pragma unroll
    for (int rg = 0; rg < 4; ++rg)
      eps[t2][rg] = *(const float*)(epp + (rg*H_ + t2*16)*4);

  __syncthreads();   // protect tiles until all waves consumed seed reads

  unsigned int wlo = 0;   // opaque 0: keeps Wh streams loop-variant (no hoist)

  // -------- main scan: 2 light barriers/step, single-buffered tiles --------
  for (int s = 0; s < NSTEP_; ++s){
    // VALU phase (u complete from prev step's MFMA phase)
    _Float16 dzh[2][4], dzl[2][4];
    unsigned char dz8[2][4];
    #pragma unroll
    for (int t2 = 0; t2 < 2; ++t2)
      #pragma unroll
      for (int rg = 0; rg < 4; ++rg){
        float uf = fmaf(INV16_, u8F[t2][rg], uF[t2][rg]) + bfv[t2];
        float ug = fmaf(INV16_, u8G[t2][rg], uG[t2][rg]) + bgv[t2];
        float f = tanh_fast(uf);
        float g = sigm_fast(ug);
        float dz = fmaf(g, sqdt * eps[t2][rg], f * dt);
        _Float16 dh = (_Float16)dz;
        _Float16 dl = (_Float16)(dz - (float)dh);
        dzh[t2][rg] = dh; dzl[t2][rg] = dl;
        dz8[t2][rg] = __hip_cvt_float_to_fp8(dz, __HIP_SATFINITE, __HIP_E4M3);
        zreg[t2][rg] += (float)dh + (float)dl;   // master == what u tracks
      }

    // Tile writes (single buffer: prev step's reads completed at last barB)
    #pragma unroll
    for (int t2 = 0; t2 < 2; ++t2)
      #pragma unroll
      for (int rg = 0; rg < 4; ++rg){
        zst[woff[t2][rg]] = dzh[t2][rg];
        zlt[woff[t2][rg]] = dzl[t2][rg];
        z8t[w8off_[t2][rg]] = dz8[t2][rg];
      }

    BARRIER_LGKM();   // barA: tiles visible; global traffic stays in flight

    if (s + 1 < NSTEP_){
      epp += (size_t)B_ * H_ * 4;   // advance to step s+1's noise
      #pragma unroll
      for (int t2 = 0; t2 < 2; ++t2)
        #pragma unroll
        for (int rg = 0; rg < 4; ++rg)
          eps[t2][rg] = *(const float*)(epp + (rg*H_ + t2*16)*4);
    }
    if (s >= HWIN_ - 1){
      int sl = s - (HWIN_ - 1);
      #pragma unroll
      for (int t2 = 0; t2 < 2; ++t2)
        #pragma unroll
        for (int rg = 0; rg < 4; ++rg)
          zhist[zh0 + (size_t)rg*(OUT_T_*H_) + sl*H_ + t2*16] = (_Float16)zreg[t2][rg];
    }

    if (s + 1 < NSTEP_){
      const char* pf = pfB + wlo;
      const char* pg = pgB + wlo;
      // 2-kt-deep register prefetch pipeline for Wh (decouple load latency)
      half8 whf[2][2], whg[2][2];
      #pragma unroll
      for (int t2 = 0; t2 < 2; ++t2){
        whf[0][t2] = *(const half8*)(pf + (0*2 + t2)*1024);
        whg[0][t2] = *(const half8*)(pg + (0*2 + t2)*1024);
        whf[1][t2] = *(const half8*)(pf + (1*2 + t2)*1024);
        whg[1][t2] = *(const half8*)(pg + (1*2 + t2)*1024);
      }
      #pragma unroll
      for (int kt = 0; kt < 8; ++kt){
        half8 ah = *(const half8*)&zst[aoff[kt]];
        half8 al = *(const half8*)&zlt[aoff[kt]];
        long  a8 = *(const long*)&z8t[a8off[kt]];
        half8 f0 = whf[kt & 1][0], f1 = whf[kt & 1][1];
        half8 g0 = whg[kt & 1][0], g1 = whg[kt & 1][1];
        if (kt + 2 < 8){
          #pragma unroll
          for (int t2 = 0; t2 < 2; ++t2){
            whf[kt & 1][t2] = *(const half8*)(pf + ((kt+2)*2 + t2)*1024);
            whg[kt & 1][t2] = *(const half8*)(pg + ((kt+2)*2 + t2)*1024);
          }
        }
        int e0 = (kt*H_ + n0a)*32 + 8*hi;
        long w8f0 = *(const long*)(w8lds + e0);
        long w8f1 = *(const long*)(w8lds + e0 + 512);           // +16 cols
        long w8g0 = *(const long*)(w8lds + 65536 + e0);
        long w8g1 = *(const long*)(w8lds + 65536 + e0 + 512);
        uF[0]  = __builtin_amdgcn_mfma_f32_16x16x32_f16(ah, f0, uF[0], 0,0,0);
        uF[1]  = __builtin_amdgcn_mfma_f32_16x16x32_f16(ah, f1, uF[1], 0,0,0);
        uG[0]  = __builtin_amdgcn_mfma_f32_16x16x32_f16(ah, g0, uG[0], 0,0,0);
        uG[1]  = __builtin_amdgcn_mfma_f32_16x16x32_f16(ah, g1, uG[1], 0,0,0);
        uF[0]  = __builtin_amdgcn_mfma_f32_16x16x32_f16(al, f0, uF[0], 0,0,0);
        uF[1]  = __builtin_amdgcn_mfma_f32_16x16x32_f16(al, f1, uF[1], 0,0,0);
        uG[0]  = __builtin_amdgcn_mfma_f32_16x16x32_f16(al, g0, uG[0], 0,0,0);
        uG[1]  = __builtin_amdgcn_mfma_f32_16x16x32_f16(al, g1, uG[1], 0,0,0);
        u8F[0] = __builtin_amdgcn_mfma_f32_16x16x32_fp8_fp8(a8, w8f0, u8F[0], 0,0,0);
        u8F[1] = __builtin_amdgcn_mfma_f32_16x16x32_fp8_fp8(a8, w8f1, u8F[1], 0,0,0);
        u8G[0] = __builtin_amdgcn_mfma_f32_16x16x32_fp8_fp8(a8, w8g0, u8G[0], 0,0,0);
        u8G[1] = __builtin_amdgcn_mfma_f32_16x16x32_fp8_fp8(a8, w8g1, u8G[1], 0,0,0);
      }
    }

    BARRIER_LGKM();   // barB: this step's tile reads done before next write
    asm volatile("" : "+v"(wlo));
  }
}

// ---------------- head kernel: pred_y = relu(h@W1+b1)@W2 + b2 ----------------
__global__ __launch_bounds__(256) void head_kernel(
    const _Float16* __restrict__ zhist,
    const _Float16* __restrict__ W1P,
    const _Float16* __restrict__ W2P,
    const float* __restrict__ b1,
    const float* __restrict__ b2,
    float* __restrict__ out)
{
  __shared__ __align__(16) _Float16 hbuf[64 * H_];  // 32 KB, swizzled
  __shared__ __align__(16) _Float16 ubuf[64 * H_];  // 32 KB, swizzled

  const int tid  = threadIdx.x;
  const int lane = tid & 63;
  const int wv   = tid >> 6;   // 0..3
  const int lo   = lane & 15;
  const int hi   = lane >> 4;
  const int m0   = blockIdx.x * 64;

  for (int c = tid; c < 64 * 32; c += 256){
    int rr = c >> 5, c8 = (c & 31) * 8;
    *(half8*)&hbuf[(rr * H_ + c8) ^ ((rr & 7) << 3)] =
        *(const half8*)&zhist[(size_t)(m0 + rr) * H_ + c8];
  }

  half8 w1f[4][8];
  #pragma unroll
  for (int nt = 0; nt < 4; ++nt){
    int n0 = 64*wv + 16*nt + lo;
    #pragma unroll
    for (int kt = 0; kt < 8; ++kt)
      w1f[nt][kt] = *(const half8*)(W1P + (kt*H_ + n0)*32 + 8*hi);
  }
  half8 w2f[8];
  #pragma unroll
  for (int kt = 0; kt < 8; ++kt)
    w2f[kt] = *(const half8*)(W2P + (kt*COUT_ + 16*wv + lo)*32 + 8*hi);

  float b1v[4];
  #pragma unroll
  for (int nt = 0; nt < 4; ++nt) b1v[nt] = b1[64*wv + 16*nt + lo];
  float b2v = b2[16*wv + lo];

  __syncthreads();

  // Stage 1: U = relu(h @ W1 + b1)
  for (int mt = 0; mt < 4; ++mt){
    half8 a[8];
    #pragma unroll
    for (int kt = 0; kt < 8; ++kt)
      a[kt] = *(const half8*)&hbuf[((mt*16 + lo) * H_ + kt*32 + hi*8) ^ ((lo & 7) << 3)];
    #pragma unroll
    for (int nt = 0; nt < 4; ++nt){
      floatx4 acc = {0.f,0.f,0.f,0.f};
      #pragma unroll
      for (int kt = 0; kt < 8; ++kt)
        acc = __builtin_amdgcn_mfma_f32_16x16x32_f16(a[kt], w1f[nt][kt], acc, 0,0,0);
      #pragma unroll
      for (int rg = 0; rg < 4; ++rg){
        float u = fmaxf(acc[rg] + b1v[nt], 0.0f);
        int rr = mt*16 + hi*4 + rg;
        int cc = 64*wv + 16*nt + lo;
        ubuf[(rr * H_ + cc) ^ ((rr & 7) << 3)] = (_Float16)u;
      }
    }
  }
  __syncthreads();

  // Stage 2: out = U @ W2 + b2
  for (int mt = 0; mt < 4; ++mt){
    half8 a[8];
    #pragma unroll
    for (int kt = 0; kt < 8; ++kt)
      a[kt] = *(const half8*)&ubuf[((mt*16 + lo) * H_ + kt*32 + hi*8) ^ ((lo & 7) << 3)];
    floatx4 acc = {0.f,0.f,0.f,0.f};
    #pragma unroll
    for (int kt = 0; kt < 8; ++kt)
      acc = __builtin_amdgcn_mfma_f32_16x16x32_f16(a[kt], w2f[kt], acc, 0,0,0);
    #pragma unroll
    for (int rg = 0; rg < 4; ++rg)
      out[(size_t)(m0 + mt*16 + hi*4 + rg) * COUT_ + 16*wv + lo] = acc[rg] + b2v;
  }
}

extern "C" void kernel_launch(void* const* d_in, const int* in_sizes, int n_in,
                              void* d_out, int out_size, void* d_ws, size_t ws_size,
                              hipStream_t stream) {
  const float* times  = (const float*)d_in[0];
  const float* coeffs = (const float*)d_in[1];
  const float* noise  = (const float*)d_in[2];
  const float* W_init = (const float*)d_in[3];
  const float* b_init = (const float*)d_in[4];
  const float* Wf     = (const float*)d_in[5];
  const float* bf     = (const float*)d_in[6];
  const float* Wg     = (const float*)d_in[7];
  const float* bg     = (const float*)d_in[8];
  const float* W1     = (const float*)d_in[9];
  const float* b1     = (const float*)d_in[10];
  const float* W2     = (const float*)d_in[11];
  const float* b2     = (const float*)d_in[12];

  // Workspace layout
  char* ws = (char*)d_ws;
  _Float16*      zhist = (_Float16*)(ws);                    // 8388608
  _Float16*      WfPh  = (_Float16*)(ws + 8388608);          // 131072 (wave-major)
  _Float16*      WgPh  = (_Float16*)(ws + 8519680);          // 131072 (wave-major)
  unsigned char* W8lF  = (unsigned char*)(ws + 8650752);     // 65536
  unsigned char* W8lG  = (unsigned char*)(ws + 8716288);     // 65536
  _Float16*      W1Ph  = (_Float16*)(ws + 8781824);          // 131072
  _Float16*      W2Ph  = (_Float16*)(ws + 8978432);          // 32768

  packFG_kernel<<<(H_*H_ + 255)/256, 256, 0, stream>>>(Wf, WfPh, W8lF);
  packFG_kernel<<<(H_*H_ + 255)/256, 256, 0, stream>>>(Wg, WgPh, W8lG);
  pack_kernel<<<(H_*H_ + 255)/256, 256, 0, stream>>>(W1, W1Ph, H_, H_);
  pack_kernel<<<(H_*COUT_ + 255)/256, 256, 0, stream>>>(W2, W2Ph, H_, COUT_);

  hipFuncSetAttribute((const void*)scan_kernel,
                      hipFuncAttributeMaxDynamicSharedMemorySize, LDS_TOTAL_);
  scan_kernel<<<B_ / NB_, 512, LDS_TOTAL_, stream>>>(
      times, coeffs, noise, W_init, b_init, bf, bg,
      WfPh, WgPh, W8lF, W8lG, zhist);

  head_kernel<<<(B_ * OUT_T_) / 64, 256, 0, stream>>>(zhist, W1Ph, W2Ph, b1, b2,
                                                      (float*)d_out);
}